// Round 15
// baseline (92.397 us; speedup 1.0000x reference)
//
#include <hip/hip_runtime.h>
#include <cstddef>

// Shapes: B=4, H=W=D=16, C=32, N=4096, Dout=13; out (4,16,16,13,32) f32.

typedef float f32x4 __attribute__((ext_vector_type(4)));
typedef short s16x8 __attribute__((ext_vector_type(8)));

#define SQRT_LOG2E 1.2011224087864498f   // xb scaled so QK^T lands in exp2 domain
#define C2SHIFT    57.70780163555854f    // 40*log2(e)

// HW packed f32->bf16. Used UNIFORMLY (xb, xtf, P-pack): within-pair lo/hi
// permutation cancels in every MFMA contraction (both operands same packing).
__device__ inline unsigned cvtpk(float a, float b) {
  unsigned r;
  asm("v_cvt_pk_bf16_f32 %0, %1, %2" : "=v"(r) : "v"(a), "v"(b));
  return r;
}

// ---------------------------------------------------------------------------
// K1: prep. xb = bf16(x*sqrt(log2e)) [b][n][32]; xtf = X^T A-frag tiles.
// ---------------------------------------------------------------------------
__global__ __launch_bounds__(256) void k_prep(
    const float* __restrict__ x, ushort* __restrict__ xb, ushort* __restrict__ xtf)
{
  int t = blockIdx.x * 256 + threadIdx.x;          // 0..65535
  const float4* xs = (const float4*)x;
  float4 v0 = xs[2 * t], v1 = xs[2 * t + 1];
  uint4 o;
  o.x = cvtpk(v0.x * SQRT_LOG2E, v0.y * SQRT_LOG2E);
  o.y = cvtpk(v0.z * SQRT_LOG2E, v0.w * SQRT_LOG2E);
  o.z = cvtpk(v1.x * SQRT_LOG2E, v1.y * SQRT_LOG2E);
  o.w = cvtpk(v1.z * SQRT_LOG2E, v1.w * SQRT_LOG2E);
  ((uint4*)xb)[t] = o;

  int b = t >> 14, r2 = t & 16383;
  int ktile = r2 >> 7, r3 = r2 & 127;
  int h = r3 >> 6, lane = r3 & 63;
  int g = lane >> 4, c = h * 16 + (lane & 15);
  const float* src = x + (((size_t)b * 4096 + ktile * 32 + 8 * g) * 32 + c);
  float w[8];
#pragma unroll
  for (int j = 0; j < 8; ++j) w[j] = src[(size_t)j * 32];
  uint4 u;
  u.x = cvtpk(w[0], w[1]); u.y = cvtpk(w[2], w[3]);
  u.z = cvtpk(w[4], w[5]); u.w = cvtpk(w[6], w[7]);
  ((uint4*)xtf)[(size_t)((b * 128 + ktile) * 2 + h) * 64 + lane] = u;
}

// ---------------------------------------------------------------------------
// K2: Gram partials via MFMA from xtf. 32 blocks x 256 thr; partials -> pG/pS.
// ---------------------------------------------------------------------------
__global__ __launch_bounds__(256) void k_gramP(
    const ushort* __restrict__ xtf, float* __restrict__ pG, float* __restrict__ pS)
{
  int b = blockIdx.x >> 3, ks = blockIdx.x & 7;
  int wid = threadIdx.x >> 6, lane = threadIdx.x & 63;
  const ushort* xtb = xtf + (size_t)b * 131072;
  int t0 = ks * 16 + wid * 4;
  f32x4 z = {0.f, 0.f, 0.f, 0.f};
  f32x4 G00 = z, G01 = z, G10 = z, G11 = z, s0 = z, s1 = z;
  s16x8 ones;
#pragma unroll
  for (int j = 0; j < 8; ++j) ones[j] = (short)0x3F80;
  for (int t = t0; t < t0 + 4; ++t) {
    const ushort* xt = xtb + (size_t)t * 1024 + lane * 8;
    s16x8 a0 = *(const s16x8*)(xt);
    s16x8 a1 = *(const s16x8*)(xt + 512);
    G00 = __builtin_amdgcn_mfma_f32_16x16x32_bf16(a0, a0, G00, 0, 0, 0);
    G01 = __builtin_amdgcn_mfma_f32_16x16x32_bf16(a0, a1, G01, 0, 0, 0);
    G10 = __builtin_amdgcn_mfma_f32_16x16x32_bf16(a1, a0, G10, 0, 0, 0);
    G11 = __builtin_amdgcn_mfma_f32_16x16x32_bf16(a1, a1, G11, 0, 0, 0);
    s0  = __builtin_amdgcn_mfma_f32_16x16x32_bf16(a0, ones, s0, 0, 0, 0);
    s1  = __builtin_amdgcn_mfma_f32_16x16x32_bf16(a1, ones, s1, 0, 0, 0);
  }
  int p = blockIdx.x * 4 + wid;
  int g = lane >> 4, c16 = lane & 15;
  float* pg = pG + (size_t)p * 1024;
#pragma unroll
  for (int hr = 0; hr < 2; ++hr)
#pragma unroll
    for (int hc = 0; hc < 2; ++hc) {
      f32x4 v = hr ? (hc ? G11 : G10) : (hc ? G01 : G00);
#pragma unroll
      for (int r = 0; r < 4; ++r)
        pg[(16 * hr + 4 * g + r) * 32 + 16 * hc + c16] = v[r];
    }
  if (c16 == 0) {
#pragma unroll
    for (int hr = 0; hr < 2; ++hr) {
      f32x4 v = hr ? s1 : s0;
#pragma unroll
      for (int r = 0; r < 4; ++r) pS[p * 32 + 16 * hr + 4 * g + r] = v[r];
    }
  }
}

// ---------------------------------------------------------------------------
// K3: algebra. Parallel reduce of partials + stage B with LDS weights.
// 4 blocks x 1024 thr (proven R14).
// ---------------------------------------------------------------------------
__global__ __launch_bounds__(1024) void k_alg(
    const float* __restrict__ pG, const float* __restrict__ pS,
    const float* __restrict__ wq, const float* __restrict__ bq,
    const float* __restrict__ wk, const float* __restrict__ bk,
    const float* __restrict__ wv, const float* __restrict__ bv,
    const float* __restrict__ gamma,
    const float* __restrict__ wpos, const float* __restrict__ bpos,
    float* __restrict__ w2, float* __restrict__ b2)
{
  __shared__ float G[1024], s[32], t1[1024], att[1024], M[1024], mvec[32];
  __shared__ float wqS[1024], wkS[1024], wvS[1024], wpoS[4096];
  int b = blockIdx.x, tid = threadIdx.x;
  if (tid < 256)      ((float4*)wqS)[tid] = ((const float4*)wq)[tid];
  else if (tid < 512) ((float4*)wkS)[tid - 256] = ((const float4*)wk)[tid - 256];
  else if (tid < 768) ((float4*)wvS)[tid - 512] = ((const float4*)wv)[tid - 512];
  ((float4*)wpoS)[tid] = ((const float4*)wpos)[tid];

  {
    const float* pg = pG + (size_t)b * 32 * 1024 + tid;
    float g0 = 0.f;
#pragma unroll
    for (int j = 0; j < 32; ++j) g0 += pg[(size_t)j * 1024];
    G[tid] = g0;
  }
  if (tid < 32) {
    const float* ps = pS + b * 32 * 32 + tid;
    float sv = 0.f;
#pragma unroll
    for (int j = 0; j < 32; ++j) sv += ps[j * 32];
    s[tid] = sv;
  }
  __syncthreads();

  int c = tid >> 5, f = tid & 31;
  float t = 0.f;
#pragma unroll
  for (int j = 0; j < 32; ++j) t = fmaf(G[c * 32 + j], wkS[j * 32 + f], t);
  t1[tid] = t;
  __syncthreads();
  float swk = 0.f, swq = 0.f;
#pragma unroll
  for (int j = 0; j < 32; ++j) {
    swk = fmaf(s[j], wkS[j * 32 + f], swk);
    swq = fmaf(s[j], wqS[j * 32 + c], swq);
  }
  float e = 0.f;
#pragma unroll
  for (int i = 0; i < 32; ++i) e = fmaf(wqS[i * 32 + c], t1[i * 32 + f], e);
  e += bq[c] * (swk + 4096.f * bk[f]) + swq * bk[f];
  float m_ = e;
  for (int off = 16; off; off >>= 1) m_ = fmaxf(m_, __shfl_xor(m_, off, 32));
  float pr = __expf(e - m_);
  float sum = pr;
  for (int off = 16; off; off >>= 1) sum += __shfl_xor(sum, off, 32);
  att[tid] = pr / sum;
  __syncthreads();
  float mm = 0.f;
#pragma unroll
  for (int j = 0; j < 32; ++j) mm = fmaf(wvS[c * 32 + j], att[f * 32 + j], mm);
  M[c * 32 + f] = mm;
  if (c == 0) {
    float mv = 0.f;
#pragma unroll
    for (int j = 0; j < 32; ++j) mv = fmaf(bv[j], att[f * 32 + j], mv);
    mvec[f] = mv;
  }
  __syncthreads();
  float gam = gamma[0];
  for (int kd = 0; kd < 4; ++kd) {
    float acc = 0.f;
#pragma unroll
    for (int j = 0; j < 32; ++j)
      acc = fmaf(M[c * 32 + j], wpoS[(kd * 32 + j) * 32 + f], acc);
    w2[((b * 4 + kd) * 32 + c) * 32 + f] = gam * acc + wpoS[(kd * 32 + c) * 32 + f];
  }
  if (c == 0) {
    float acc = 0.f;
#pragma unroll
    for (int kd = 0; kd < 4; ++kd)
#pragma unroll
      for (int j = 0; j < 32; ++j)
        acc = fmaf(mvec[j], wpoS[(kd * 32 + j) * 32 + tid], acc);
    b2[b * 32 + tid] = gam * acc + bpos[tid];
  }
}

// ---------------------------------------------------------------------------
// K4: fused flash + conv. 16 waves: 2 row-subgroups x 8 key-splits; each wave
// carries 2 q-fragments (32 q-rows) -> HALVED L2 traffic vs R13 (256 MB) and
// 2x compute per loaded tile. Explicit 2-deep register ping-pong prefetch
// hides L2 latency. Partials combined via LDS float atomicAdd (R12-proven).
// grid (64 rowgroups, 4 b) x 1024 thr.
// ---------------------------------------------------------------------------
struct TileRegs { s16x8 kf0a, kf1a, kf0b, kf1b, a0a, a1a, a0b, a1b; };

__device__ inline void load_tile(TileRegs& T, const ushort* xbb, const ushort* xtb,
                                 int kt, int kap, int g, int lane) {
  const ushort* kra = xbb + (size_t)kt * 32;
  const ushort* krb = kra + 1024;                  // +32 keys
  T.kf0a = *(const s16x8*)(kra + (size_t)kap * 32 + 8 * g);
  T.kf1a = *(const s16x8*)(kra + (size_t)(kap + 4) * 32 + 8 * g);
  T.kf0b = *(const s16x8*)(krb + (size_t)kap * 32 + 8 * g);
  T.kf1b = *(const s16x8*)(krb + (size_t)(kap + 4) * 32 + 8 * g);
  const ushort* xt = xtb + (size_t)(kt >> 5) * 1024 + lane * 8;
  T.a0a = *(const s16x8*)(xt);
  T.a1a = *(const s16x8*)(xt + 512);
  T.a0b = *(const s16x8*)(xt + 1024);
  T.a1b = *(const s16x8*)(xt + 1536);
}

__global__ __launch_bounds__(1024) void k_fused(
    const ushort* __restrict__ xb, const ushort* __restrict__ xtf,
    const float* __restrict__ x, const float* __restrict__ beta,
    const float* __restrict__ wch, const float* __restrict__ bch,
    const float* __restrict__ w2, const float* __restrict__ b2,
    float* __restrict__ out)
{
  __shared__ float sS[64][33];                     // attnout sums (padded)
  __shared__ float Ls[64];
  __shared__ float4 wcS[1024], wpS[1024];
  __shared__ float bcS[32], bpS[32];
  int rg = blockIdx.x, b = blockIdx.y, tid = threadIdx.x;

  for (int i = tid; i < 64 * 33; i += 1024) ((float*)sS)[i] = 0.f;
  if (tid < 64) Ls[tid] = 0.f;
  wcS[tid] = ((const float4*)wch)[tid];
  wpS[tid] = ((const float4*)(w2 + (size_t)b * 4096))[tid];
  if (tid < 32) { bcS[tid] = bch[tid]; bpS[tid] = b2[b * 32 + tid]; }
  __syncthreads();

  int wid = tid >> 6, lane = tid & 63, g = lane >> 4, c16 = lane & 15;
  int wid2 = wid & 1, kh = wid >> 1;               // row-subgroup(2), key-split(8)
  int qw = rg * 64 + wid2 * 32;
  const ushort* xbb = xb + ((size_t)b << 17);
  const ushort* xtb = xtf + (size_t)b * 131072;

  s16x8 qA = *(const s16x8*)(xbb + (qw + c16) * 32 + 8 * g);
  s16x8 qB = *(const s16x8*)(xbb + (qw + 16 + c16) * 32 + 8 * g);
  f32x4 z = {0.f, 0.f, 0.f, 0.f};
  f32x4 minit = {-C2SHIFT, -C2SHIFT, -C2SHIFT, -C2SHIFT};
  f32x4 oA0 = z, oA1 = z, oB0 = z, oB1 = z, lacA = z, lacB = z;
  s16x8 ones;
#pragma unroll
  for (int j = 0; j < 8; ++j) ones[j] = (short)0x3F80;
  int kap = ((c16 >> 2) << 3) + (c16 & 3);         // kappa(c16)
  int k0 = kh * 512;

#define COMPUTE(T)                                                             \
  {                                                                            \
    __builtin_amdgcn_s_setprio(1);                                             \
    f32x4 e0 = __builtin_amdgcn_mfma_f32_16x16x32_bf16(T.kf0a, qA, minit, 0, 0, 0); \
    f32x4 e1 = __builtin_amdgcn_mfma_f32_16x16x32_bf16(T.kf1a, qA, minit, 0, 0, 0); \
    f32x4 e2 = __builtin_amdgcn_mfma_f32_16x16x32_bf16(T.kf0b, qA, minit, 0, 0, 0); \
    f32x4 e3 = __builtin_amdgcn_mfma_f32_16x16x32_bf16(T.kf1b, qA, minit, 0, 0, 0); \
    f32x4 f0 = __builtin_amdgcn_mfma_f32_16x16x32_bf16(T.kf0a, qB, minit, 0, 0, 0); \
    f32x4 f1 = __builtin_amdgcn_mfma_f32_16x16x32_bf16(T.kf1a, qB, minit, 0, 0, 0); \
    f32x4 f2 = __builtin_amdgcn_mfma_f32_16x16x32_bf16(T.kf0b, qB, minit, 0, 0, 0); \
    f32x4 f3 = __builtin_amdgcn_mfma_f32_16x16x32_bf16(T.kf1b, qB, minit, 0, 0, 0); \
    __builtin_amdgcn_s_setprio(0);                                             \
    f32x4 pa0, pa1, pa2, pa3, pb0, pb1, pb2, pb3;                              \
    _Pragma("unroll")                                                          \
    for (int r = 0; r < 4; ++r) {                                              \
      pa0[r] = __builtin_amdgcn_exp2f(e0[r]);                                  \
      pa1[r] = __builtin_amdgcn_exp2f(e1[r]);                                  \
      pa2[r] = __builtin_amdgcn_exp2f(e2[r]);                                  \
      pa3[r] = __builtin_amdgcn_exp2f(e3[r]);                                  \
      pb0[r] = __builtin_amdgcn_exp2f(f0[r]);                                  \
      pb1[r] = __builtin_amdgcn_exp2f(f1[r]);                                  \
      pb2[r] = __builtin_amdgcn_exp2f(f2[r]);                                  \
      pb3[r] = __builtin_amdgcn_exp2f(f3[r]);                                  \
    }                                                                          \
    uint4 uAa = make_uint4(cvtpk(pa0[0], pa0[1]), cvtpk(pa0[2], pa0[3]),       \
                           cvtpk(pa1[0], pa1[1]), cvtpk(pa1[2], pa1[3]));      \
    uint4 uAb = make_uint4(cvtpk(pa2[0], pa2[1]), cvtpk(pa2[2], pa2[3]),       \
                           cvtpk(pa3[0], pa3[1]), cvtpk(pa3[2], pa3[3]));      \
    uint4 uBa = make_uint4(cvtpk(pb0[0], pb0[1]), cvtpk(pb0[2], pb0[3]),       \
                           cvtpk(pb1[0], pb1[1]), cvtpk(pb1[2], pb1[3]));      \
    uint4 uBb = make_uint4(cvtpk(pb2[0], pb2[1]), cvtpk(pb2[2], pb2[3]),       \
                           cvtpk(pb3[0], pb3[1]), cvtpk(pb3[2], pb3[3]));      \
    s16x8 fpAa = __builtin_bit_cast(s16x8, uAa);                               \
    s16x8 fpAb = __builtin_bit_cast(s16x8, uAb);                               \
    s16x8 fpBa = __builtin_bit_cast(s16x8, uBa);                               \
    s16x8 fpBb = __builtin_bit_cast(s16x8, uBb);                               \
    __builtin_amdgcn_s_setprio(1);                                             \
    oA0 = __builtin_amdgcn_mfma_f32_16x16x32_bf16(T.a0a, fpAa, oA0, 0, 0, 0);  \
    oA1 = __builtin_amdgcn_mfma_f32_16x16x32_bf16(T.a1a, fpAa, oA1, 0, 0, 0);  \
    oA0 = __builtin_amdgcn_mfma_f32_16x16x32_bf16(T.a0b, fpAb, oA0, 0, 0, 0);  \
    oA1 = __builtin_amdgcn_mfma_f32_16x16x32_bf16(T.a1b, fpAb, oA1, 0, 0, 0);  \
    oB0 = __builtin_amdgcn_mfma_f32_16x16x32_bf16(T.a0a, fpBa, oB0, 0, 0, 0);  \
    oB1 = __builtin_amdgcn_mfma_f32_16x16x32_bf16(T.a1a, fpBa, oB1, 0, 0, 0);  \
    oB0 = __builtin_amdgcn_mfma_f32_16x16x32_bf16(T.a0b, fpBb, oB0, 0, 0, 0);  \
    oB1 = __builtin_amdgcn_mfma_f32_16x16x32_bf16(T.a1b, fpBb, oB1, 0, 0, 0);  \
    lacA = __builtin_amdgcn_mfma_f32_16x16x32_bf16(ones, fpAa, lacA, 0, 0, 0); \
    lacA = __builtin_amdgcn_mfma_f32_16x16x32_bf16(ones, fpAb, lacA, 0, 0, 0); \
    lacB = __builtin_amdgcn_mfma_f32_16x16x32_bf16(ones, fpBa, lacB, 0, 0, 0); \
    lacB = __builtin_amdgcn_mfma_f32_16x16x32_bf16(ones, fpBb, lacB, 0, 0, 0); \
    __builtin_amdgcn_s_setprio(0);                                             \
  }

  TileRegs Tc, Tn;
  load_tile(Tc, xbb, xtb, k0, kap, g, lane);
#pragma unroll
  for (int i = 0; i < 8; i += 2) {
    load_tile(Tn, xbb, xtb, k0 + ((i + 1) & 7) * 64, kap, g, lane);
    COMPUTE(Tc);
    load_tile(Tc, xbb, xtb, k0 + ((i + 2) & 7) * 64, kap, g, lane);
    COMPUTE(Tn);
  }
#undef COMPUTE

  // accumulate partials (8 kh-waves per row-subgroup) via LDS atomics
  {
    int rA = wid2 * 32 + c16, rB = rA + 16;
    if (g == 0) { atomicAdd(&Ls[rA], lacA[0]); atomicAdd(&Ls[rB], lacB[0]); }
#pragma unroll
    for (int r = 0; r < 4; ++r) {
      atomicAdd(&sS[rA][4 * g + r], oA0[r]);
      atomicAdd(&sS[rA][16 + 4 * g + r], oA1[r]);
      atomicAdd(&sS[rB][4 * g + r], oB0[r]);
      atomicAdd(&sS[rB][16 + 4 * g + r], oB1[r]);
    }
  }
  __syncthreads();
  if (tid < 64) {
    float scv = beta[0] / Ls[tid];
#pragma unroll
    for (int c = 0; c < 32; ++c) sS[tid][c] *= scv;
  }
  __syncthreads();

  // conv3d(1,1,4) + relu both branches; 416 active threads (52 rows x 8 fq).
  if (tid < 416) {
    int row2 = tid >> 3, fq = tid & 7;
    int hw_l = row2 / 13, dout = row2 % 13;
    int rbase = hw_l * 16 + dout;
    size_t xrow = ((size_t)b * 4096 + (size_t)(rg * 4 + hw_l) * 16 + dout) * 32;
    float accC[4], accP[4];
#pragma unroll
    for (int j = 0; j < 4; ++j) { accC[j] = bcS[fq * 4 + j]; accP[j] = bpS[fq * 4 + j]; }
    for (int kd = 0; kd < 4; ++kd) {
      const float4* xr4 = (const float4*)(x + xrow + (size_t)kd * 32);
      const float* srow = sS[rbase + kd];
#pragma unroll
      for (int c4 = 0; c4 < 8; ++c4) {
        float4 xv = xr4[c4];
#pragma unroll
        for (int e = 0; e < 4; ++e) {
          float xve = (e == 0 ? xv.x : e == 1 ? xv.y : e == 2 ? xv.z : xv.w);
          float cve = srow[4 * c4 + e] + xve;      // ca = beta*o/L + x
          int wbase = (kd * 32 + 4 * c4 + e) * 8 + fq;
          float4 w1 = wcS[wbase];
          accC[0] = fmaf(cve, w1.x, accC[0]);
          accC[1] = fmaf(cve, w1.y, accC[1]);
          accC[2] = fmaf(cve, w1.z, accC[2]);
          accC[3] = fmaf(cve, w1.w, accC[3]);
          float4 w2v = wpS[wbase];
          accP[0] = fmaf(xve, w2v.x, accP[0]);
          accP[1] = fmaf(xve, w2v.y, accP[1]);
          accP[2] = fmaf(xve, w2v.z, accP[2]);
          accP[3] = fmaf(xve, w2v.w, accP[3]);
        }
      }
    }
    int gid = b * 3328 + (rg * 4 + hw_l) * 13 + dout;
    float* orow = out + (size_t)gid * 32 + fq * 4;
    float4 o;
    o.x = fmaxf(accC[0], 0.f) + fmaxf(accP[0], 0.f);
    o.y = fmaxf(accC[1], 0.f) + fmaxf(accP[1], 0.f);
    o.z = fmaxf(accC[2], 0.f) + fmaxf(accP[2], 0.f);
    o.w = fmaxf(accC[3], 0.f) + fmaxf(accP[3], 0.f);
    *(float4*)orow = o;
  }
}

extern "C" void kernel_launch(void* const* d_in, const int* in_sizes, int n_in,
                              void* d_out, int out_size, void* d_ws, size_t ws_size,
                              hipStream_t stream)
{
  const float* x     = (const float*)d_in[0];
  const float* beta  = (const float*)d_in[1];
  const float* wq    = (const float*)d_in[2];
  const float* bq    = (const float*)d_in[3];
  const float* wk    = (const float*)d_in[4];
  const float* bk    = (const float*)d_in[5];
  const float* wv    = (const float*)d_in[6];
  const float* bv    = (const float*)d_in[7];
  const float* gamma = (const float*)d_in[8];
  const float* wch   = (const float*)d_in[9];
  const float* bch   = (const float*)d_in[10];
  const float* wpos  = (const float*)d_in[11];
  const float* bpos  = (const float*)d_in[12];
  float* out = (float*)d_out;
  float* ws  = (float*)d_ws;

  ushort* xb  = (ushort*)(ws + 0);        // 512 KB
  ushort* xtf = (ushort*)(ws + 262144);   // 512 KB
  float*  w2  = ws + 524288;              // 64 KB
  float*  b2  = ws + 540672;              // 512 B
  float*  pG  = ws + 540800;              // 512 KB
  float*  pS  = ws + 671872;              // 16 KB

  hipLaunchKernelGGL(k_prep,  dim3(256),   dim3(256),  0, stream, x, xb, xtf);
  hipLaunchKernelGGL(k_gramP, dim3(32),    dim3(256),  0, stream, xtf, pG, pS);
  hipLaunchKernelGGL(k_alg,   dim3(4),     dim3(1024), 0, stream,
                     pG, pS, wq, bq, wk, bk, wv, bv, gamma, wpos, bpos, w2, b2);
  hipLaunchKernelGGL(k_fused, dim3(64, 4), dim3(1024), 0, stream,
                     xb, xtf, x, beta, wch, bch, w2, b2, out);
}

// Round 16
// 65.602 us; speedup vs baseline: 1.4085x; 1.4085x over previous
//
#include <hip/hip_runtime.h>
#include <cstddef>

// Shapes: B=4, H=W=D=16, C=32, N=4096, Dout=13; out (4,16,16,13,32) f32.

typedef float f32x4 __attribute__((ext_vector_type(4)));
typedef short s16x8 __attribute__((ext_vector_type(8)));

#define SQRT_LOG2E 1.2011224087864498f   // xb scaled so QK^T lands in exp2 domain
#define C2SHIFT    57.70780163555854f    // 40*log2(e)

// HW packed f32->bf16. Used UNIFORMLY (xb, xtf, P-pack): within-pair lo/hi
// permutation cancels in every MFMA contraction (both operands same packing).
__device__ inline unsigned cvtpk(float a, float b) {
  unsigned r;
  asm("v_cvt_pk_bf16_f32 %0, %1, %2" : "=v"(r) : "v"(a), "v"(b));
  return r;
}

// ---------------------------------------------------------------------------
// K1: prep. xb = bf16(x*sqrt(log2e)) [b][n][32]; xtf = X^T A-frag tiles.
// ---------------------------------------------------------------------------
__global__ __launch_bounds__(256) void k_prep(
    const float* __restrict__ x, ushort* __restrict__ xb, ushort* __restrict__ xtf)
{
  int t = blockIdx.x * 256 + threadIdx.x;          // 0..65535
  const float4* xs = (const float4*)x;
  float4 v0 = xs[2 * t], v1 = xs[2 * t + 1];
  uint4 o;
  o.x = cvtpk(v0.x * SQRT_LOG2E, v0.y * SQRT_LOG2E);
  o.y = cvtpk(v0.z * SQRT_LOG2E, v0.w * SQRT_LOG2E);
  o.z = cvtpk(v1.x * SQRT_LOG2E, v1.y * SQRT_LOG2E);
  o.w = cvtpk(v1.z * SQRT_LOG2E, v1.w * SQRT_LOG2E);
  ((uint4*)xb)[t] = o;

  int b = t >> 14, r2 = t & 16383;
  int ktile = r2 >> 7, r3 = r2 & 127;
  int h = r3 >> 6, lane = r3 & 63;
  int g = lane >> 4, c = h * 16 + (lane & 15);
  const float* src = x + (((size_t)b * 4096 + ktile * 32 + 8 * g) * 32 + c);
  float w[8];
#pragma unroll
  for (int j = 0; j < 8; ++j) w[j] = src[(size_t)j * 32];
  uint4 u;
  u.x = cvtpk(w[0], w[1]); u.y = cvtpk(w[2], w[3]);
  u.z = cvtpk(w[4], w[5]); u.w = cvtpk(w[6], w[7]);
  ((uint4*)xtf)[(size_t)((b * 128 + ktile) * 2 + h) * 64 + lane] = u;
}

// ---------------------------------------------------------------------------
// K2: Gram partials via MFMA from xtf. 32 blocks x 256 thr; partials -> pG/pS.
// ---------------------------------------------------------------------------
__global__ __launch_bounds__(256) void k_gramP(
    const ushort* __restrict__ xtf, float* __restrict__ pG, float* __restrict__ pS)
{
  int b = blockIdx.x >> 3, ks = blockIdx.x & 7;
  int wid = threadIdx.x >> 6, lane = threadIdx.x & 63;
  const ushort* xtb = xtf + (size_t)b * 131072;
  int t0 = ks * 16 + wid * 4;
  f32x4 z = {0.f, 0.f, 0.f, 0.f};
  f32x4 G00 = z, G01 = z, G10 = z, G11 = z, s0 = z, s1 = z;
  s16x8 ones;
#pragma unroll
  for (int j = 0; j < 8; ++j) ones[j] = (short)0x3F80;
  for (int t = t0; t < t0 + 4; ++t) {
    const ushort* xt = xtb + (size_t)t * 1024 + lane * 8;
    s16x8 a0 = *(const s16x8*)(xt);
    s16x8 a1 = *(const s16x8*)(xt + 512);
    G00 = __builtin_amdgcn_mfma_f32_16x16x32_bf16(a0, a0, G00, 0, 0, 0);
    G01 = __builtin_amdgcn_mfma_f32_16x16x32_bf16(a0, a1, G01, 0, 0, 0);
    G10 = __builtin_amdgcn_mfma_f32_16x16x32_bf16(a1, a0, G10, 0, 0, 0);
    G11 = __builtin_amdgcn_mfma_f32_16x16x32_bf16(a1, a1, G11, 0, 0, 0);
    s0  = __builtin_amdgcn_mfma_f32_16x16x32_bf16(a0, ones, s0, 0, 0, 0);
    s1  = __builtin_amdgcn_mfma_f32_16x16x32_bf16(a1, ones, s1, 0, 0, 0);
  }
  int p = blockIdx.x * 4 + wid;
  int g = lane >> 4, c16 = lane & 15;
  float* pg = pG + (size_t)p * 1024;
#pragma unroll
  for (int hr = 0; hr < 2; ++hr)
#pragma unroll
    for (int hc = 0; hc < 2; ++hc) {
      f32x4 v = hr ? (hc ? G11 : G10) : (hc ? G01 : G00);
#pragma unroll
      for (int r = 0; r < 4; ++r)
        pg[(16 * hr + 4 * g + r) * 32 + 16 * hc + c16] = v[r];
    }
  if (c16 == 0) {
#pragma unroll
    for (int hr = 0; hr < 2; ++hr) {
      f32x4 v = hr ? s1 : s0;
#pragma unroll
      for (int r = 0; r < 4; ++r) pS[p * 32 + 16 * hr + 4 * g + r] = v[r];
    }
  }
}

// ---------------------------------------------------------------------------
// K3: algebra. Parallel reduce of partials + stage B with LDS weights.
// 4 blocks x 1024 thr (proven R14).
// ---------------------------------------------------------------------------
__global__ __launch_bounds__(1024) void k_alg(
    const float* __restrict__ pG, const float* __restrict__ pS,
    const float* __restrict__ wq, const float* __restrict__ bq,
    const float* __restrict__ wk, const float* __restrict__ bk,
    const float* __restrict__ wv, const float* __restrict__ bv,
    const float* __restrict__ gamma,
    const float* __restrict__ wpos, const float* __restrict__ bpos,
    float* __restrict__ w2, float* __restrict__ b2)
{
  __shared__ float G[1024], s[32], t1[1024], att[1024], M[1024], mvec[32];
  __shared__ float wqS[1024], wkS[1024], wvS[1024], wpoS[4096];
  int b = blockIdx.x, tid = threadIdx.x;
  if (tid < 256)      ((float4*)wqS)[tid] = ((const float4*)wq)[tid];
  else if (tid < 512) ((float4*)wkS)[tid - 256] = ((const float4*)wk)[tid - 256];
  else if (tid < 768) ((float4*)wvS)[tid - 512] = ((const float4*)wv)[tid - 512];
  ((float4*)wpoS)[tid] = ((const float4*)wpos)[tid];

  {
    const float* pg = pG + (size_t)b * 32 * 1024 + tid;
    float g0 = 0.f;
#pragma unroll
    for (int j = 0; j < 32; ++j) g0 += pg[(size_t)j * 1024];
    G[tid] = g0;
  }
  if (tid < 32) {
    const float* ps = pS + b * 32 * 32 + tid;
    float sv = 0.f;
#pragma unroll
    for (int j = 0; j < 32; ++j) sv += ps[j * 32];
    s[tid] = sv;
  }
  __syncthreads();

  int c = tid >> 5, f = tid & 31;
  float t = 0.f;
#pragma unroll
  for (int j = 0; j < 32; ++j) t = fmaf(G[c * 32 + j], wkS[j * 32 + f], t);
  t1[tid] = t;
  __syncthreads();
  float swk = 0.f, swq = 0.f;
#pragma unroll
  for (int j = 0; j < 32; ++j) {
    swk = fmaf(s[j], wkS[j * 32 + f], swk);
    swq = fmaf(s[j], wqS[j * 32 + c], swq);
  }
  float e = 0.f;
#pragma unroll
  for (int i = 0; i < 32; ++i) e = fmaf(wqS[i * 32 + c], t1[i * 32 + f], e);
  e += bq[c] * (swk + 4096.f * bk[f]) + swq * bk[f];
  float m_ = e;
  for (int off = 16; off; off >>= 1) m_ = fmaxf(m_, __shfl_xor(m_, off, 32));
  float pr = __expf(e - m_);
  float sum = pr;
  for (int off = 16; off; off >>= 1) sum += __shfl_xor(sum, off, 32);
  att[tid] = pr / sum;
  __syncthreads();
  float mm = 0.f;
#pragma unroll
  for (int j = 0; j < 32; ++j) mm = fmaf(wvS[c * 32 + j], att[f * 32 + j], mm);
  M[c * 32 + f] = mm;
  if (c == 0) {
    float mv = 0.f;
#pragma unroll
    for (int j = 0; j < 32; ++j) mv = fmaf(bv[j], att[f * 32 + j], mv);
    mvec[f] = mv;
  }
  __syncthreads();
  float gam = gamma[0];
  for (int kd = 0; kd < 4; ++kd) {
    float acc = 0.f;
#pragma unroll
    for (int j = 0; j < 32; ++j)
      acc = fmaf(M[c * 32 + j], wpoS[(kd * 32 + j) * 32 + f], acc);
    w2[((b * 4 + kd) * 32 + c) * 32 + f] = gam * acc + wpoS[(kd * 32 + c) * 32 + f];
  }
  if (c == 0) {
    float acc = 0.f;
#pragma unroll
    for (int kd = 0; kd < 4; ++kd)
#pragma unroll
      for (int j = 0; j < 32; ++j)
        acc = fmaf(mvec[j], wpoS[(kd * 32 + j) * 32 + tid], acc);
    b2[b * 32 + tid] = gam * acc + bpos[tid];
  }
}

// ---------------------------------------------------------------------------
// K4: fused flash + conv. 1024 thr = 16 waves = 2 row-subgroups x 8 key-
// splits; each wave carries F=2 q-fragments (32 q-rows, 512 keys) -> half of
// R13's L2 traffic at the SAME wave count. Plain inline loads (R11-proven
// body — no struct, no manual prefetch; R15's TileRegs spilled to scratch).
// __launch_bounds__(1024,4) grants the 128-VGPR budget so F=2 fits.
// Partials combined via LDS float atomicAdd. grid (64 rowgroups, 4 b).
// ---------------------------------------------------------------------------
__global__ __launch_bounds__(1024, 4) void k_fused(
    const ushort* __restrict__ xb, const ushort* __restrict__ xtf,
    const float* __restrict__ x, const float* __restrict__ beta,
    const float* __restrict__ wch, const float* __restrict__ bch,
    const float* __restrict__ w2, const float* __restrict__ b2,
    float* __restrict__ out)
{
  __shared__ float sS[64][33];                     // attnout sums (padded)
  __shared__ float Ls[64];
  __shared__ float4 wcS[1024], wpS[1024];
  __shared__ float bcS[32], bpS[32];
  int rg = blockIdx.x, b = blockIdx.y, tid = threadIdx.x;

  for (int i = tid; i < 64 * 33; i += 1024) ((float*)sS)[i] = 0.f;
  if (tid < 64) Ls[tid] = 0.f;
  wcS[tid] = ((const float4*)wch)[tid];
  wpS[tid] = ((const float4*)(w2 + (size_t)b * 4096))[tid];
  if (tid < 32) { bcS[tid] = bch[tid]; bpS[tid] = b2[b * 32 + tid]; }
  __syncthreads();

  int wid = tid >> 6, lane = tid & 63, g = lane >> 4, c16 = lane & 15;
  int wid2 = wid & 1, kh = wid >> 1;               // row-subgroup(2), key-split(8)
  int qw = rg * 64 + wid2 * 32;
  const ushort* xbb = xb + ((size_t)b << 17);
  const ushort* xtb = xtf + (size_t)b * 131072;

  s16x8 qA = *(const s16x8*)(xbb + (qw + c16) * 32 + 8 * g);
  s16x8 qB = *(const s16x8*)(xbb + (qw + 16 + c16) * 32 + 8 * g);
  f32x4 z = {0.f, 0.f, 0.f, 0.f};
  f32x4 minit = {-C2SHIFT, -C2SHIFT, -C2SHIFT, -C2SHIFT};
  f32x4 oA0 = z, oA1 = z, oB0 = z, oB1 = z, lacA = z, lacB = z;
  s16x8 ones;
#pragma unroll
  for (int j = 0; j < 8; ++j) ones[j] = (short)0x3F80;
  int kap = ((c16 >> 2) << 3) + (c16 & 3);         // kappa(c16)
  int k0 = kh * 512;

  for (int kt = k0; kt < k0 + 512; kt += 32) {
    const ushort* kr = xbb + (size_t)kt * 32;
    s16x8 kf0 = *(const s16x8*)(kr + (size_t)kap * 32 + 8 * g);
    s16x8 kf1 = *(const s16x8*)(kr + (size_t)(kap + 4) * 32 + 8 * g);
    const ushort* xt = xtb + (size_t)(kt >> 5) * 1024 + lane * 8;
    s16x8 a0 = *(const s16x8*)(xt);
    s16x8 a1 = *(const s16x8*)(xt + 512);

    __builtin_amdgcn_s_setprio(1);
    f32x4 e0 = __builtin_amdgcn_mfma_f32_16x16x32_bf16(kf0, qA, minit, 0, 0, 0);
    f32x4 e1 = __builtin_amdgcn_mfma_f32_16x16x32_bf16(kf1, qA, minit, 0, 0, 0);
    f32x4 f0 = __builtin_amdgcn_mfma_f32_16x16x32_bf16(kf0, qB, minit, 0, 0, 0);
    f32x4 f1 = __builtin_amdgcn_mfma_f32_16x16x32_bf16(kf1, qB, minit, 0, 0, 0);
    __builtin_amdgcn_s_setprio(0);
    f32x4 pA0, pA1, pB0, pB1;
#pragma unroll
    for (int r = 0; r < 4; ++r) {
      pA0[r] = __builtin_amdgcn_exp2f(e0[r]);
      pA1[r] = __builtin_amdgcn_exp2f(e1[r]);
      pB0[r] = __builtin_amdgcn_exp2f(f0[r]);
      pB1[r] = __builtin_amdgcn_exp2f(f1[r]);
    }
    uint4 uA = make_uint4(cvtpk(pA0[0], pA0[1]), cvtpk(pA0[2], pA0[3]),
                          cvtpk(pA1[0], pA1[1]), cvtpk(pA1[2], pA1[3]));
    uint4 uB = make_uint4(cvtpk(pB0[0], pB0[1]), cvtpk(pB0[2], pB0[3]),
                          cvtpk(pB1[0], pB1[1]), cvtpk(pB1[2], pB1[3]));
    s16x8 fpA = __builtin_bit_cast(s16x8, uA);
    s16x8 fpB = __builtin_bit_cast(s16x8, uB);

    __builtin_amdgcn_s_setprio(1);
    oA0 = __builtin_amdgcn_mfma_f32_16x16x32_bf16(a0, fpA, oA0, 0, 0, 0);
    oA1 = __builtin_amdgcn_mfma_f32_16x16x32_bf16(a1, fpA, oA1, 0, 0, 0);
    oB0 = __builtin_amdgcn_mfma_f32_16x16x32_bf16(a0, fpB, oB0, 0, 0, 0);
    oB1 = __builtin_amdgcn_mfma_f32_16x16x32_bf16(a1, fpB, oB1, 0, 0, 0);
    lacA = __builtin_amdgcn_mfma_f32_16x16x32_bf16(ones, fpA, lacA, 0, 0, 0);
    lacB = __builtin_amdgcn_mfma_f32_16x16x32_bf16(ones, fpB, lacB, 0, 0, 0);
    __builtin_amdgcn_s_setprio(0);
  }

  // accumulate partials (8 kh-waves per row) via LDS float atomics
  {
    int rA = wid2 * 32 + c16, rB = rA + 16;
    if (g == 0) { atomicAdd(&Ls[rA], lacA[0]); atomicAdd(&Ls[rB], lacB[0]); }
#pragma unroll
    for (int r = 0; r < 4; ++r) {
      atomicAdd(&sS[rA][4 * g + r], oA0[r]);
      atomicAdd(&sS[rA][16 + 4 * g + r], oA1[r]);
      atomicAdd(&sS[rB][4 * g + r], oB0[r]);
      atomicAdd(&sS[rB][16 + 4 * g + r], oB1[r]);
    }
  }
  __syncthreads();
  if (tid < 64) {
    float scv = beta[0] / Ls[tid];
#pragma unroll
    for (int c = 0; c < 32; ++c) sS[tid][c] *= scv;
  }
  __syncthreads();

  // conv3d(1,1,4) + relu both branches; 416 active threads (52 rows x 8 fq).
  if (tid < 416) {
    int row2 = tid >> 3, fq = tid & 7;
    int hw_l = row2 / 13, dout = row2 % 13;
    int rbase = hw_l * 16 + dout;
    size_t xrow = ((size_t)b * 4096 + (size_t)(rg * 4 + hw_l) * 16 + dout) * 32;
    float accC[4], accP[4];
#pragma unroll
    for (int j = 0; j < 4; ++j) { accC[j] = bcS[fq * 4 + j]; accP[j] = bpS[fq * 4 + j]; }
    for (int kd = 0; kd < 4; ++kd) {
      const float4* xr4 = (const float4*)(x + xrow + (size_t)kd * 32);
      const float* srow = sS[rbase + kd];
#pragma unroll
      for (int c4 = 0; c4 < 8; ++c4) {
        float4 xv = xr4[c4];
#pragma unroll
        for (int e = 0; e < 4; ++e) {
          float xve = (e == 0 ? xv.x : e == 1 ? xv.y : e == 2 ? xv.z : xv.w);
          float cve = srow[4 * c4 + e] + xve;      // ca = beta*o/L + x
          int wbase = (kd * 32 + 4 * c4 + e) * 8 + fq;
          float4 w1 = wcS[wbase];
          accC[0] = fmaf(cve, w1.x, accC[0]);
          accC[1] = fmaf(cve, w1.y, accC[1]);
          accC[2] = fmaf(cve, w1.z, accC[2]);
          accC[3] = fmaf(cve, w1.w, accC[3]);
          float4 w2v = wpS[wbase];
          accP[0] = fmaf(xve, w2v.x, accP[0]);
          accP[1] = fmaf(xve, w2v.y, accP[1]);
          accP[2] = fmaf(xve, w2v.z, accP[2]);
          accP[3] = fmaf(xve, w2v.w, accP[3]);
        }
      }
    }
    int gid = b * 3328 + (rg * 4 + hw_l) * 13 + dout;
    float* orow = out + (size_t)gid * 32 + fq * 4;
    float4 o;
    o.x = fmaxf(accC[0], 0.f) + fmaxf(accP[0], 0.f);
    o.y = fmaxf(accC[1], 0.f) + fmaxf(accP[1], 0.f);
    o.z = fmaxf(accC[2], 0.f) + fmaxf(accP[2], 0.f);
    o.w = fmaxf(accC[3], 0.f) + fmaxf(accP[3], 0.f);
    *(float4*)orow = o;
  }
}

extern "C" void kernel_launch(void* const* d_in, const int* in_sizes, int n_in,
                              void* d_out, int out_size, void* d_ws, size_t ws_size,
                              hipStream_t stream)
{
  const float* x     = (const float*)d_in[0];
  const float* beta  = (const float*)d_in[1];
  const float* wq    = (const float*)d_in[2];
  const float* bq    = (const float*)d_in[3];
  const float* wk    = (const float*)d_in[4];
  const float* bk    = (const float*)d_in[5];
  const float* wv    = (const float*)d_in[6];
  const float* bv    = (const float*)d_in[7];
  const float* gamma = (const float*)d_in[8];
  const float* wch   = (const float*)d_in[9];
  const float* bch   = (const float*)d_in[10];
  const float* wpos  = (const float*)d_in[11];
  const float* bpos  = (const float*)d_in[12];
  float* out = (float*)d_out;
  float* ws  = (float*)d_ws;

  ushort* xb  = (ushort*)(ws + 0);        // 512 KB
  ushort* xtf = (ushort*)(ws + 262144);   // 512 KB
  float*  w2  = ws + 524288;              // 64 KB
  float*  b2  = ws + 540672;              // 512 B
  float*  pG  = ws + 540800;              // 512 KB
  float*  pS  = ws + 671872;              // 16 KB

  hipLaunchKernelGGL(k_prep,  dim3(256),   dim3(256),  0, stream, x, xb, xtf);
  hipLaunchKernelGGL(k_gramP, dim3(32),    dim3(256),  0, stream, xtf, pG, pS);
  hipLaunchKernelGGL(k_alg,   dim3(4),     dim3(1024), 0, stream,
                     pG, pS, wq, bq, wk, bk, wv, bv, gamma, wpos, bpos, w2, b2);
  hipLaunchKernelGGL(k_fused, dim3(64, 4), dim3(1024), 0, stream,
                     xb, xtf, x, beta, wch, bch, w2, b2, out);
}

// Round 17
// 58.017 us; speedup vs baseline: 1.5926x; 1.1307x over previous
//
#include <hip/hip_runtime.h>
#include <cstddef>

// Shapes: B=4, H=W=D=16, C=32, N=4096, Dout=13; out (4,16,16,13,32) f32.

typedef float f32x4 __attribute__((ext_vector_type(4)));
typedef short s16x8 __attribute__((ext_vector_type(8)));

#define SQRT_LOG2E 1.2011224087864498f   // xb scaled so QK^T lands in exp2 domain
#define C2SHIFT    57.70780163555854f    // 40*log2(e)

// HW packed f32->bf16. Used UNIFORMLY (xb, xtf, P-pack): within-pair lo/hi
// permutation cancels in every MFMA contraction (both operands same packing).
__device__ inline unsigned cvtpk(float a, float b) {
  unsigned r;
  asm("v_cvt_pk_bf16_f32 %0, %1, %2" : "=v"(r) : "v"(a), "v"(b));
  return r;
}

// ---------------------------------------------------------------------------
// K1: prep. xb = bf16(x*sqrt(log2e)) [b][n][32]; xtf = X^T A-frag tiles.
// ---------------------------------------------------------------------------
__global__ __launch_bounds__(256) void k_prep(
    const float* __restrict__ x, ushort* __restrict__ xb, ushort* __restrict__ xtf)
{
  int t = blockIdx.x * 256 + threadIdx.x;          // 0..65535
  const float4* xs = (const float4*)x;
  float4 v0 = xs[2 * t], v1 = xs[2 * t + 1];
  uint4 o;
  o.x = cvtpk(v0.x * SQRT_LOG2E, v0.y * SQRT_LOG2E);
  o.y = cvtpk(v0.z * SQRT_LOG2E, v0.w * SQRT_LOG2E);
  o.z = cvtpk(v1.x * SQRT_LOG2E, v1.y * SQRT_LOG2E);
  o.w = cvtpk(v1.z * SQRT_LOG2E, v1.w * SQRT_LOG2E);
  ((uint4*)xb)[t] = o;

  int b = t >> 14, r2 = t & 16383;
  int ktile = r2 >> 7, r3 = r2 & 127;
  int h = r3 >> 6, lane = r3 & 63;
  int g = lane >> 4, c = h * 16 + (lane & 15);
  const float* src = x + (((size_t)b * 4096 + ktile * 32 + 8 * g) * 32 + c);
  float w[8];
#pragma unroll
  for (int j = 0; j < 8; ++j) w[j] = src[(size_t)j * 32];
  uint4 u;
  u.x = cvtpk(w[0], w[1]); u.y = cvtpk(w[2], w[3]);
  u.z = cvtpk(w[4], w[5]); u.w = cvtpk(w[6], w[7]);
  ((uint4*)xtf)[(size_t)((b * 128 + ktile) * 2 + h) * 64 + lane] = u;
}

// ---------------------------------------------------------------------------
// K2: Gram partials via MFMA from xtf. 32 blocks x 256 thr; partials -> pG/pS.
// ---------------------------------------------------------------------------
__global__ __launch_bounds__(256) void k_gramP(
    const ushort* __restrict__ xtf, float* __restrict__ pG, float* __restrict__ pS)
{
  int b = blockIdx.x >> 3, ks = blockIdx.x & 7;
  int wid = threadIdx.x >> 6, lane = threadIdx.x & 63;
  const ushort* xtb = xtf + (size_t)b * 131072;
  int t0 = ks * 16 + wid * 4;
  f32x4 z = {0.f, 0.f, 0.f, 0.f};
  f32x4 G00 = z, G01 = z, G10 = z, G11 = z, s0 = z, s1 = z;
  s16x8 ones;
#pragma unroll
  for (int j = 0; j < 8; ++j) ones[j] = (short)0x3F80;
  for (int t = t0; t < t0 + 4; ++t) {
    const ushort* xt = xtb + (size_t)t * 1024 + lane * 8;
    s16x8 a0 = *(const s16x8*)(xt);
    s16x8 a1 = *(const s16x8*)(xt + 512);
    G00 = __builtin_amdgcn_mfma_f32_16x16x32_bf16(a0, a0, G00, 0, 0, 0);
    G01 = __builtin_amdgcn_mfma_f32_16x16x32_bf16(a0, a1, G01, 0, 0, 0);
    G10 = __builtin_amdgcn_mfma_f32_16x16x32_bf16(a1, a0, G10, 0, 0, 0);
    G11 = __builtin_amdgcn_mfma_f32_16x16x32_bf16(a1, a1, G11, 0, 0, 0);
    s0  = __builtin_amdgcn_mfma_f32_16x16x32_bf16(a0, ones, s0, 0, 0, 0);
    s1  = __builtin_amdgcn_mfma_f32_16x16x32_bf16(a1, ones, s1, 0, 0, 0);
  }
  int p = blockIdx.x * 4 + wid;
  int g = lane >> 4, c16 = lane & 15;
  float* pg = pG + (size_t)p * 1024;
#pragma unroll
  for (int hr = 0; hr < 2; ++hr)
#pragma unroll
    for (int hc = 0; hc < 2; ++hc) {
      f32x4 v = hr ? (hc ? G11 : G10) : (hc ? G01 : G00);
#pragma unroll
      for (int r = 0; r < 4; ++r)
        pg[(16 * hr + 4 * g + r) * 32 + 16 * hc + c16] = v[r];
    }
  if (c16 == 0) {
#pragma unroll
    for (int hr = 0; hr < 2; ++hr) {
      f32x4 v = hr ? s1 : s0;
#pragma unroll
      for (int r = 0; r < 4; ++r) pS[p * 32 + 16 * hr + 4 * g + r] = v[r];
    }
  }
}

// ---------------------------------------------------------------------------
// K3: algebra. Parallel reduce of partials + stage B with LDS weights.
// 4 blocks x 1024 thr (proven R14).
// ---------------------------------------------------------------------------
__global__ __launch_bounds__(1024) void k_alg(
    const float* __restrict__ pG, const float* __restrict__ pS,
    const float* __restrict__ wq, const float* __restrict__ bq,
    const float* __restrict__ wk, const float* __restrict__ bk,
    const float* __restrict__ wv, const float* __restrict__ bv,
    const float* __restrict__ gamma,
    const float* __restrict__ wpos, const float* __restrict__ bpos,
    float* __restrict__ w2, float* __restrict__ b2)
{
  __shared__ float G[1024], s[32], t1[1024], att[1024], M[1024], mvec[32];
  __shared__ float wqS[1024], wkS[1024], wvS[1024], wpoS[4096];
  int b = blockIdx.x, tid = threadIdx.x;
  if (tid < 256)      ((float4*)wqS)[tid] = ((const float4*)wq)[tid];
  else if (tid < 512) ((float4*)wkS)[tid - 256] = ((const float4*)wk)[tid - 256];
  else if (tid < 768) ((float4*)wvS)[tid - 512] = ((const float4*)wv)[tid - 512];
  ((float4*)wpoS)[tid] = ((const float4*)wpos)[tid];

  {
    const float* pg = pG + (size_t)b * 32 * 1024 + tid;
    float g0 = 0.f;
#pragma unroll
    for (int j = 0; j < 32; ++j) g0 += pg[(size_t)j * 1024];
    G[tid] = g0;
  }
  if (tid < 32) {
    const float* ps = pS + b * 32 * 32 + tid;
    float sv = 0.f;
#pragma unroll
    for (int j = 0; j < 32; ++j) sv += ps[j * 32];
    s[tid] = sv;
  }
  __syncthreads();

  int c = tid >> 5, f = tid & 31;
  float t = 0.f;
#pragma unroll
  for (int j = 0; j < 32; ++j) t = fmaf(G[c * 32 + j], wkS[j * 32 + f], t);
  t1[tid] = t;
  __syncthreads();
  float swk = 0.f, swq = 0.f;
#pragma unroll
  for (int j = 0; j < 32; ++j) {
    swk = fmaf(s[j], wkS[j * 32 + f], swk);
    swq = fmaf(s[j], wqS[j * 32 + c], swq);
  }
  float e = 0.f;
#pragma unroll
  for (int i = 0; i < 32; ++i) e = fmaf(wqS[i * 32 + c], t1[i * 32 + f], e);
  e += bq[c] * (swk + 4096.f * bk[f]) + swq * bk[f];
  float m_ = e;
  for (int off = 16; off; off >>= 1) m_ = fmaxf(m_, __shfl_xor(m_, off, 32));
  float pr = __expf(e - m_);
  float sum = pr;
  for (int off = 16; off; off >>= 1) sum += __shfl_xor(sum, off, 32);
  att[tid] = pr / sum;
  __syncthreads();
  float mm = 0.f;
#pragma unroll
  for (int j = 0; j < 32; ++j) mm = fmaf(wvS[c * 32 + j], att[f * 32 + j], mm);
  M[c * 32 + f] = mm;
  if (c == 0) {
    float mv = 0.f;
#pragma unroll
    for (int j = 0; j < 32; ++j) mv = fmaf(bv[j], att[f * 32 + j], mv);
    mvec[f] = mv;
  }
  __syncthreads();
  float gam = gamma[0];
  for (int kd = 0; kd < 4; ++kd) {
    float acc = 0.f;
#pragma unroll
    for (int j = 0; j < 32; ++j)
      acc = fmaf(M[c * 32 + j], wpoS[(kd * 32 + j) * 32 + f], acc);
    w2[((b * 4 + kd) * 32 + c) * 32 + f] = gam * acc + wpoS[(kd * 32 + c) * 32 + f];
  }
  if (c == 0) {
    float acc = 0.f;
#pragma unroll
    for (int kd = 0; kd < 4; ++kd)
#pragma unroll
      for (int j = 0; j < 32; ++j)
        acc = fmaf(mvec[j], wpoS[(kd * 32 + j) * 32 + tid], acc);
    b2[b * 32 + tid] = gam * acc + bpos[tid];
  }
}

// ---------------------------------------------------------------------------
// K4: fused flash + conv (R14 structure: F=1, 4 row-subgroups x 4 key-
// quarters, 16 iters of 64 keys) + MANUAL 2-DEEP PIPELINE with pre-declared
// NAMED registers (no struct/array -> no R15 scratch spill). Next tile's 8
// b128 loads issue before current tile's compute. grid (64,4) x 1024 thr.
// ---------------------------------------------------------------------------
union FusedSh {
  struct { f32x4 pO0[3][4][64]; f32x4 pO1[3][4][64]; float pL[3][4][64]; } ph1;
  struct { float4 wc[1024]; float4 wp[1024]; } ph2;
};

__global__ __launch_bounds__(1024) void k_fused(
    const ushort* __restrict__ xb, const ushort* __restrict__ xtf,
    const float* __restrict__ x, const float* __restrict__ beta,
    const float* __restrict__ wch, const float* __restrict__ bch,
    const float* __restrict__ w2, const float* __restrict__ b2,
    float* __restrict__ out)
{
  __shared__ FusedSh u;
  __shared__ float sS[64][32];
  __shared__ float bcS[32], bpS[32];
  int rg = blockIdx.x, b = blockIdx.y, tid = threadIdx.x;
  if (tid < 32) { bcS[tid] = bch[tid]; bpS[tid] = b2[b * 32 + tid]; }

  int wid = tid >> 6, lane = tid & 63, g = lane >> 4, c16 = lane & 15;
  int wid2 = wid & 3, kh = wid >> 2;               // row-subgroup, key-quarter
  int qw = rg * 64 + wid2 * 16;
  const ushort* xbb = xb + ((size_t)b << 17);
  const ushort* xtb = xtf + (size_t)b * 131072;

  s16x8 qA = *(const s16x8*)(xbb + (qw + c16) * 32 + 8 * g);
  f32x4 z = {0.f, 0.f, 0.f, 0.f};
  f32x4 minit = {-C2SHIFT, -C2SHIFT, -C2SHIFT, -C2SHIFT};
  f32x4 oA0 = z, oA1 = z, lac = z;
  s16x8 ones;
#pragma unroll
  for (int j = 0; j < 8; ++j) ones[j] = (short)0x3F80;
  int kap = ((c16 >> 2) << 3) + (c16 & 3);         // kappa(c16)
  int k0 = kh * 1024;

  // two named register sets for the 2-deep pipeline (NO struct/array)
  s16x8 ckf0a, ckf1a, ckf0b, ckf1b, ca0a, ca1a, ca0b, ca1b;
  s16x8 nkf0a, nkf1a, nkf0b, nkf1b, na0a, na1a, na0b, na1b;

#define LOADT(P, kt) {                                                         \
    const ushort* kra = xbb + (size_t)(kt) * 32;                               \
    const ushort* krb = kra + 1024;                                            \
    P##kf0a = *(const s16x8*)(kra + (size_t)kap * 32 + 8 * g);                 \
    P##kf1a = *(const s16x8*)(kra + (size_t)(kap + 4) * 32 + 8 * g);           \
    P##kf0b = *(const s16x8*)(krb + (size_t)kap * 32 + 8 * g);                 \
    P##kf1b = *(const s16x8*)(krb + (size_t)(kap + 4) * 32 + 8 * g);           \
    const ushort* xt = xtb + (size_t)((kt) >> 5) * 1024 + lane * 8;            \
    P##a0a = *(const s16x8*)(xt);                                              \
    P##a1a = *(const s16x8*)(xt + 512);                                        \
    P##a0b = *(const s16x8*)(xt + 1024);                                       \
    P##a1b = *(const s16x8*)(xt + 1536);                                       \
  }

#define COMPUTET(P) {                                                          \
    __builtin_amdgcn_s_setprio(1);                                             \
    f32x4 e0 = __builtin_amdgcn_mfma_f32_16x16x32_bf16(P##kf0a, qA, minit, 0, 0, 0); \
    f32x4 e1 = __builtin_amdgcn_mfma_f32_16x16x32_bf16(P##kf1a, qA, minit, 0, 0, 0); \
    f32x4 e2 = __builtin_amdgcn_mfma_f32_16x16x32_bf16(P##kf0b, qA, minit, 0, 0, 0); \
    f32x4 e3 = __builtin_amdgcn_mfma_f32_16x16x32_bf16(P##kf1b, qA, minit, 0, 0, 0); \
    __builtin_amdgcn_s_setprio(0);                                             \
    f32x4 p0, p1, p2, p3;                                                      \
    _Pragma("unroll")                                                          \
    for (int r = 0; r < 4; ++r) {                                              \
      p0[r] = __builtin_amdgcn_exp2f(e0[r]);                                   \
      p1[r] = __builtin_amdgcn_exp2f(e1[r]);                                   \
      p2[r] = __builtin_amdgcn_exp2f(e2[r]);                                   \
      p3[r] = __builtin_amdgcn_exp2f(e3[r]);                                   \
    }                                                                          \
    uint4 uA = make_uint4(cvtpk(p0[0], p0[1]), cvtpk(p0[2], p0[3]),            \
                          cvtpk(p1[0], p1[1]), cvtpk(p1[2], p1[3]));           \
    uint4 uB = make_uint4(cvtpk(p2[0], p2[1]), cvtpk(p2[2], p2[3]),            \
                          cvtpk(p3[0], p3[1]), cvtpk(p3[2], p3[3]));           \
    s16x8 fpa = __builtin_bit_cast(s16x8, uA);                                 \
    s16x8 fpb = __builtin_bit_cast(s16x8, uB);                                 \
    __builtin_amdgcn_s_setprio(1);                                             \
    oA0 = __builtin_amdgcn_mfma_f32_16x16x32_bf16(P##a0a, fpa, oA0, 0, 0, 0);  \
    oA1 = __builtin_amdgcn_mfma_f32_16x16x32_bf16(P##a1a, fpa, oA1, 0, 0, 0);  \
    lac = __builtin_amdgcn_mfma_f32_16x16x32_bf16(ones, fpa, lac, 0, 0, 0);    \
    oA0 = __builtin_amdgcn_mfma_f32_16x16x32_bf16(P##a0b, fpb, oA0, 0, 0, 0);  \
    oA1 = __builtin_amdgcn_mfma_f32_16x16x32_bf16(P##a1b, fpb, oA1, 0, 0, 0);  \
    lac = __builtin_amdgcn_mfma_f32_16x16x32_bf16(ones, fpb, lac, 0, 0, 0);    \
    __builtin_amdgcn_s_setprio(0);                                             \
  }

  LOADT(c, k0)
#pragma unroll
  for (int t = 0; t < 8; ++t) {
    int base = k0 + t * 128;
    LOADT(n, base + 64)
    COMPUTET(c)
    LOADT(c, k0 + ((t * 128 + 128) & 1023))   // wraps in-bounds on last trip
    COMPUTET(n)
  }
#undef LOADT
#undef COMPUTET

  // combine 4 key-quarters (additive: fixed softmax shift)
  if (kh != 0) {
    u.ph1.pO0[kh - 1][wid2][lane] = oA0;
    u.ph1.pO1[kh - 1][wid2][lane] = oA1;
    u.ph1.pL[kh - 1][wid2][lane] = lac[0];
  }
  __syncthreads();
  if (kh == 0) {
    float L = lac[0];
    f32x4 t0 = oA0, t1 = oA1;
#pragma unroll
    for (int q = 0; q < 3; ++q) {
      f32x4 q0 = u.ph1.pO0[q][wid2][lane], q1 = u.ph1.pO1[q][wid2][lane];
      L += u.ph1.pL[q][wid2][lane];
#pragma unroll
      for (int r = 0; r < 4; ++r) { t0[r] += q0[r]; t1[r] += q1[r]; }
    }
    float sc = beta[0] / L;
    int rloc = wid2 * 16 + c16;
    f32x4 v0, v1;
#pragma unroll
    for (int r = 0; r < 4; ++r) { v0[r] = t0[r] * sc; v1[r] = t1[r] * sc; }
    *(f32x4*)&sS[rloc][4 * g] = v0;
    *(f32x4*)&sS[rloc][16 + 4 * g] = v1;
  }
  __syncthreads();
  u.ph2.wc[tid] = ((const float4*)wch)[tid];
  u.ph2.wp[tid] = ((const float4*)(w2 + (size_t)b * 4096))[tid];
  __syncthreads();

  if (tid < 416) {
    int row2 = tid >> 3, fq = tid & 7;
    int hw_l = row2 / 13, dout = row2 % 13;
    int rbase = hw_l * 16 + dout;
    size_t xrow = ((size_t)b * 4096 + (size_t)(rg * 4 + hw_l) * 16 + dout) * 32;
    float accC[4], accP[4];
#pragma unroll
    for (int j = 0; j < 4; ++j) { accC[j] = bcS[fq * 4 + j]; accP[j] = bpS[fq * 4 + j]; }
    for (int kd = 0; kd < 4; ++kd) {
      const float4* xr4 = (const float4*)(x + xrow + (size_t)kd * 32);
      const float* srow = sS[rbase + kd];
#pragma unroll
      for (int c4 = 0; c4 < 8; ++c4) {
        float4 xv = xr4[c4];
#pragma unroll
        for (int e = 0; e < 4; ++e) {
          float xve = (e == 0 ? xv.x : e == 1 ? xv.y : e == 2 ? xv.z : xv.w);
          float cve = srow[4 * c4 + e] + xve;
          int wbase = (kd * 32 + 4 * c4 + e) * 8 + fq;
          float4 w1 = u.ph2.wc[wbase];
          accC[0] = fmaf(cve, w1.x, accC[0]);
          accC[1] = fmaf(cve, w1.y, accC[1]);
          accC[2] = fmaf(cve, w1.z, accC[2]);
          accC[3] = fmaf(cve, w1.w, accC[3]);
          float4 w2v = u.ph2.wp[wbase];
          accP[0] = fmaf(xve, w2v.x, accP[0]);
          accP[1] = fmaf(xve, w2v.y, accP[1]);
          accP[2] = fmaf(xve, w2v.z, accP[2]);
          accP[3] = fmaf(xve, w2v.w, accP[3]);
        }
      }
    }
    int gid = b * 3328 + (rg * 4 + hw_l) * 13 + dout;
    float* orow = out + (size_t)gid * 32 + fq * 4;
    float4 o;
    o.x = fmaxf(accC[0], 0.f) + fmaxf(accP[0], 0.f);
    o.y = fmaxf(accC[1], 0.f) + fmaxf(accP[1], 0.f);
    o.z = fmaxf(accC[2], 0.f) + fmaxf(accP[2], 0.f);
    o.w = fmaxf(accC[3], 0.f) + fmaxf(accP[3], 0.f);
    *(float4*)orow = o;
  }
}

extern "C" void kernel_launch(void* const* d_in, const int* in_sizes, int n_in,
                              void* d_out, int out_size, void* d_ws, size_t ws_size,
                              hipStream_t stream)
{
  const float* x     = (const float*)d_in[0];
  const float* beta  = (const float*)d_in[1];
  const float* wq    = (const float*)d_in[2];
  const float* bq    = (const float*)d_in[3];
  const float* wk    = (const float*)d_in[4];
  const float* bk    = (const float*)d_in[5];
  const float* wv    = (const float*)d_in[6];
  const float* bv    = (const float*)d_in[7];
  const float* gamma = (const float*)d_in[8];
  const float* wch   = (const float*)d_in[9];
  const float* bch   = (const float*)d_in[10];
  const float* wpos  = (const float*)d_in[11];
  const float* bpos  = (const float*)d_in[12];
  float* out = (float*)d_out;
  float* ws  = (float*)d_ws;

  ushort* xb  = (ushort*)(ws + 0);        // 512 KB
  ushort* xtf = (ushort*)(ws + 262144);   // 512 KB
  float*  w2  = ws + 524288;              // 64 KB
  float*  b2  = ws + 540672;              // 512 B
  float*  pG  = ws + 540800;              // 512 KB
  float*  pS  = ws + 671872;              // 16 KB

  hipLaunchKernelGGL(k_prep,  dim3(256),   dim3(256),  0, stream, x, xb, xtf);
  hipLaunchKernelGGL(k_gramP, dim3(32),    dim3(256),  0, stream, xtf, pG, pS);
  hipLaunchKernelGGL(k_alg,   dim3(4),     dim3(1024), 0, stream,
                     pG, pS, wq, bq, wk, bk, wv, bv, gamma, wpos, bpos, w2, b2);
  hipLaunchKernelGGL(k_fused, dim3(64, 4), dim3(1024), 0, stream,
                     xb, xtf, x, beta, wch, bch, w2, b2, out);
}

// Round 18
// 45.604 us; speedup vs baseline: 2.0261x; 1.2722x over previous
//
#include <hip/hip_runtime.h>
#include <cstddef>

// Shapes: B=4, H=W=D=16, C=32, N=4096, Dout=13; out (4,16,16,13,32) f32.

typedef float f32x4 __attribute__((ext_vector_type(4)));
typedef short s16x8 __attribute__((ext_vector_type(8)));

#define SQRT_LOG2E 1.2011224087864498f   // xb scaled so QK^T lands in exp2 domain
#define C2SHIFT    57.70780163555854f    // 40*log2(e)

// HW packed f32->bf16. Used UNIFORMLY (xb, xtf, P-pack): within-pair lo/hi
// permutation cancels in every MFMA contraction (both operands same packing).
__device__ inline unsigned cvtpk(float a, float b) {
  unsigned r;
  asm("v_cvt_pk_bf16_f32 %0, %1, %2" : "=v"(r) : "v"(a), "v"(b));
  return r;
}

// ---------------------------------------------------------------------------
// K1: prep. xb = bf16(x*sqrt(log2e)) [b][n][32]; xtf = X^T A-frag tiles.
// ---------------------------------------------------------------------------
__global__ __launch_bounds__(256) void k_prep(
    const float* __restrict__ x, ushort* __restrict__ xb, ushort* __restrict__ xtf)
{
  int t = blockIdx.x * 256 + threadIdx.x;          // 0..65535
  const float4* xs = (const float4*)x;
  float4 v0 = xs[2 * t], v1 = xs[2 * t + 1];
  uint4 o;
  o.x = cvtpk(v0.x * SQRT_LOG2E, v0.y * SQRT_LOG2E);
  o.y = cvtpk(v0.z * SQRT_LOG2E, v0.w * SQRT_LOG2E);
  o.z = cvtpk(v1.x * SQRT_LOG2E, v1.y * SQRT_LOG2E);
  o.w = cvtpk(v1.z * SQRT_LOG2E, v1.w * SQRT_LOG2E);
  ((uint4*)xb)[t] = o;

  int b = t >> 14, r2 = t & 16383;
  int ktile = r2 >> 7, r3 = r2 & 127;
  int h = r3 >> 6, lane = r3 & 63;
  int g = lane >> 4, c = h * 16 + (lane & 15);
  const float* src = x + (((size_t)b * 4096 + ktile * 32 + 8 * g) * 32 + c);
  float w[8];
#pragma unroll
  for (int j = 0; j < 8; ++j) w[j] = src[(size_t)j * 32];
  uint4 u;
  u.x = cvtpk(w[0], w[1]); u.y = cvtpk(w[2], w[3]);
  u.z = cvtpk(w[4], w[5]); u.w = cvtpk(w[6], w[7]);
  ((uint4*)xtf)[(size_t)((b * 128 + ktile) * 2 + h) * 64 + lane] = u;
}

// ---------------------------------------------------------------------------
// K2: Gram partials via MFMA from xtf. 32 blocks x 256 thr; partials -> pG/pS.
// ---------------------------------------------------------------------------
__global__ __launch_bounds__(256) void k_gramP(
    const ushort* __restrict__ xtf, float* __restrict__ pG, float* __restrict__ pS)
{
  int b = blockIdx.x >> 3, ks = blockIdx.x & 7;
  int wid = threadIdx.x >> 6, lane = threadIdx.x & 63;
  const ushort* xtb = xtf + (size_t)b * 131072;
  int t0 = ks * 16 + wid * 4;
  f32x4 z = {0.f, 0.f, 0.f, 0.f};
  f32x4 G00 = z, G01 = z, G10 = z, G11 = z, s0 = z, s1 = z;
  s16x8 ones;
#pragma unroll
  for (int j = 0; j < 8; ++j) ones[j] = (short)0x3F80;
  for (int t = t0; t < t0 + 4; ++t) {
    const ushort* xt = xtb + (size_t)t * 1024 + lane * 8;
    s16x8 a0 = *(const s16x8*)(xt);
    s16x8 a1 = *(const s16x8*)(xt + 512);
    G00 = __builtin_amdgcn_mfma_f32_16x16x32_bf16(a0, a0, G00, 0, 0, 0);
    G01 = __builtin_amdgcn_mfma_f32_16x16x32_bf16(a0, a1, G01, 0, 0, 0);
    G10 = __builtin_amdgcn_mfma_f32_16x16x32_bf16(a1, a0, G10, 0, 0, 0);
    G11 = __builtin_amdgcn_mfma_f32_16x16x32_bf16(a1, a1, G11, 0, 0, 0);
    s0  = __builtin_amdgcn_mfma_f32_16x16x32_bf16(a0, ones, s0, 0, 0, 0);
    s1  = __builtin_amdgcn_mfma_f32_16x16x32_bf16(a1, ones, s1, 0, 0, 0);
  }
  int p = blockIdx.x * 4 + wid;
  int g = lane >> 4, c16 = lane & 15;
  float* pg = pG + (size_t)p * 1024;
#pragma unroll
  for (int hr = 0; hr < 2; ++hr)
#pragma unroll
    for (int hc = 0; hc < 2; ++hc) {
      f32x4 v = hr ? (hc ? G11 : G10) : (hc ? G01 : G00);
#pragma unroll
      for (int r = 0; r < 4; ++r)
        pg[(16 * hr + 4 * g + r) * 32 + 16 * hc + c16] = v[r];
    }
  if (c16 == 0) {
#pragma unroll
    for (int hr = 0; hr < 2; ++hr) {
      f32x4 v = hr ? s1 : s0;
#pragma unroll
      for (int r = 0; r < 4; ++r) pS[p * 32 + 16 * hr + 4 * g + r] = v[r];
    }
  }
}

// ---------------------------------------------------------------------------
// K3: algebra. Parallel reduce of partials + stage B with LDS weights.
// 4 blocks x 1024 thr (proven R14).
// ---------------------------------------------------------------------------
__global__ __launch_bounds__(1024) void k_alg(
    const float* __restrict__ pG, const float* __restrict__ pS,
    const float* __restrict__ wq, const float* __restrict__ bq,
    const float* __restrict__ wk, const float* __restrict__ bk,
    const float* __restrict__ wv, const float* __restrict__ bv,
    const float* __restrict__ gamma,
    const float* __restrict__ wpos, const float* __restrict__ bpos,
    float* __restrict__ w2, float* __restrict__ b2)
{
  __shared__ float G[1024], s[32], t1[1024], att[1024], M[1024], mvec[32];
  __shared__ float wqS[1024], wkS[1024], wvS[1024], wpoS[4096];
  int b = blockIdx.x, tid = threadIdx.x;
  if (tid < 256)      ((float4*)wqS)[tid] = ((const float4*)wq)[tid];
  else if (tid < 512) ((float4*)wkS)[tid - 256] = ((const float4*)wk)[tid - 256];
  else if (tid < 768) ((float4*)wvS)[tid - 512] = ((const float4*)wv)[tid - 512];
  ((float4*)wpoS)[tid] = ((const float4*)wpos)[tid];

  {
    const float* pg = pG + (size_t)b * 32 * 1024 + tid;
    float g0 = 0.f;
#pragma unroll
    for (int j = 0; j < 32; ++j) g0 += pg[(size_t)j * 1024];
    G[tid] = g0;
  }
  if (tid < 32) {
    const float* ps = pS + b * 32 * 32 + tid;
    float sv = 0.f;
#pragma unroll
    for (int j = 0; j < 32; ++j) sv += ps[j * 32];
    s[tid] = sv;
  }
  __syncthreads();

  int c = tid >> 5, f = tid & 31;
  float t = 0.f;
#pragma unroll
  for (int j = 0; j < 32; ++j) t = fmaf(G[c * 32 + j], wkS[j * 32 + f], t);
  t1[tid] = t;
  __syncthreads();
  float swk = 0.f, swq = 0.f;
#pragma unroll
  for (int j = 0; j < 32; ++j) {
    swk = fmaf(s[j], wkS[j * 32 + f], swk);
    swq = fmaf(s[j], wqS[j * 32 + c], swq);
  }
  float e = 0.f;
#pragma unroll
  for (int i = 0; i < 32; ++i) e = fmaf(wqS[i * 32 + c], t1[i * 32 + f], e);
  e += bq[c] * (swk + 4096.f * bk[f]) + swq * bk[f];
  float m_ = e;
  for (int off = 16; off; off >>= 1) m_ = fmaxf(m_, __shfl_xor(m_, off, 32));
  float pr = __expf(e - m_);
  float sum = pr;
  for (int off = 16; off; off >>= 1) sum += __shfl_xor(sum, off, 32);
  att[tid] = pr / sum;
  __syncthreads();
  float mm = 0.f;
#pragma unroll
  for (int j = 0; j < 32; ++j) mm = fmaf(wvS[c * 32 + j], att[f * 32 + j], mm);
  M[c * 32 + f] = mm;
  if (c == 0) {
    float mv = 0.f;
#pragma unroll
    for (int j = 0; j < 32; ++j) mv = fmaf(bv[j], att[f * 32 + j], mv);
    mvec[f] = mv;
  }
  __syncthreads();
  float gam = gamma[0];
  for (int kd = 0; kd < 4; ++kd) {
    float acc = 0.f;
#pragma unroll
    for (int j = 0; j < 32; ++j)
      acc = fmaf(M[c * 32 + j], wpoS[(kd * 32 + j) * 32 + f], acc);
    w2[((b * 4 + kd) * 32 + c) * 32 + f] = gam * acc + wpoS[(kd * 32 + c) * 32 + f];
  }
  if (c == 0) {
    float acc = 0.f;
#pragma unroll
    for (int kd = 0; kd < 4; ++kd)
#pragma unroll
      for (int j = 0; j < 32; ++j)
        acc = fmaf(mvec[j], wpoS[(kd * 32 + j) * 32 + tid], acc);
    b2[b * 32 + tid] = gam * acc + bpos[tid];
  }
}

// ---------------------------------------------------------------------------
// K4: fused flash + conv with LDS-STAGED DOUBLE-BUFFERED K-TILES (T14).
// 16 waves = 4 row-subgroups x 4 key-quarters. Each kh-group (4 waves) stages
// its 64-key tile (4KB xb rows + 4KB xtf frags) into its own 2x8KB LDS slot;
// all 4 waves consume via ds_read_b128 (kf slot XOR-swizzled by row&3 on both
// sides). Per iter: issue t+1 global loads -> compute t -> ds_write t+1 ->
// barrier. Stage buffers UNION'd with combine/conv-weight LDS (74KB total,
// 2 blocks/CU). grid (64 rowgroups, 4 b) x 1024 thr.
// ---------------------------------------------------------------------------
union BigSh {
  char stage[4][2][8192];   // [kh][buf] : 4KB kf rows (swizzled) + 4KB xtf
  struct { f32x4 pO0[3][4][64]; f32x4 pO1[3][4][64]; float pL[3][4][64]; } ph1;
  struct { float4 wc[1024]; float4 wp[1024]; } ph2;
};

__global__ __launch_bounds__(1024) void k_fused(
    const ushort* __restrict__ xb, const ushort* __restrict__ xtf,
    const float* __restrict__ x, const float* __restrict__ beta,
    const float* __restrict__ wch, const float* __restrict__ bch,
    const float* __restrict__ w2, const float* __restrict__ b2,
    float* __restrict__ out)
{
  __shared__ BigSh u;
  __shared__ float sS[64][32];
  __shared__ float bcS[32], bpS[32];
  int rg = blockIdx.x, b = blockIdx.y, tid = threadIdx.x;
  if (tid < 32) { bcS[tid] = bch[tid]; bpS[tid] = b2[b * 32 + tid]; }

  int wid = tid >> 6, lane = tid & 63, g = lane >> 4, c16 = lane & 15;
  int wid2 = wid & 3, kh = wid >> 2;               // row-subgroup, key-quarter
  int qw = rg * 64 + wid2 * 16;
  const ushort* xbb = xb + ((size_t)b << 17);
  const ushort* xtb = xtf + (size_t)b * 131072;

  s16x8 qA = *(const s16x8*)(xbb + (qw + c16) * 32 + 8 * g);
  f32x4 z = {0.f, 0.f, 0.f, 0.f};
  f32x4 minit = {-C2SHIFT, -C2SHIFT, -C2SHIFT, -C2SHIFT};
  f32x4 oA0 = z, oA1 = z, lac = z;
  s16x8 ones;
#pragma unroll
  for (int j = 0; j < 8; ++j) ones[j] = (short)0x3F80;
  int kap = ((c16 >> 2) << 3) + (c16 & 3);         // kappa(c16)
  int k0 = kh * 1024;

  // staging identity within kh-group (4 waves = 256 threads)
  int wtid = wid2 * 64 + lane;                     // 0..255
  int srow = wtid >> 2, sslot = wtid & 3;
  int wslot = (sslot ^ (srow & 3)) << 4;           // swizzled kf byte slot
  int rslot = (g ^ (c16 & 3)) << 4;                // swizzled read slot (row&3 == c16&3 for all 4 kf reads)
  uint4 rkf, rxt;

#define LOADG(t) {                                                             \
    int kt = k0 + (t) * 64;                                                    \
    rkf = *(const uint4*)(xbb + (size_t)(kt + srow) * 32 + sslot * 8);         \
    rxt = *(const uint4*)(xtb + (size_t)(kt >> 5) * 1024 + wtid * 8);          \
  }
#define WRITES(bi) {                                                           \
    char* dst = u.stage[kh][bi];                                               \
    *(uint4*)(dst + srow * 64 + wslot) = rkf;                                  \
    *(uint4*)(dst + 4096 + wtid * 16) = rxt;                                   \
  }

  LOADG(0)
  WRITES(0)
  __syncthreads();

  for (int t = 0; t < 16; ++t) {
    if (t < 15) LOADG(t + 1)
    {
      const char* buf = u.stage[kh][t & 1];
      s16x8 kf0a = *(const s16x8*)(buf + kap * 64 + rslot);
      s16x8 kf1a = *(const s16x8*)(buf + (kap + 4) * 64 + rslot);
      s16x8 kf0b = *(const s16x8*)(buf + (32 + kap) * 64 + rslot);
      s16x8 kf1b = *(const s16x8*)(buf + (36 + kap) * 64 + rslot);
      const char* xt = buf + 4096 + lane * 16;
      s16x8 a0a = *(const s16x8*)(xt);
      s16x8 a1a = *(const s16x8*)(xt + 1024);
      s16x8 a0b = *(const s16x8*)(xt + 2048);
      s16x8 a1b = *(const s16x8*)(xt + 3072);

      __builtin_amdgcn_s_setprio(1);
      f32x4 e0 = __builtin_amdgcn_mfma_f32_16x16x32_bf16(kf0a, qA, minit, 0, 0, 0);
      f32x4 e1 = __builtin_amdgcn_mfma_f32_16x16x32_bf16(kf1a, qA, minit, 0, 0, 0);
      f32x4 e2 = __builtin_amdgcn_mfma_f32_16x16x32_bf16(kf0b, qA, minit, 0, 0, 0);
      f32x4 e3 = __builtin_amdgcn_mfma_f32_16x16x32_bf16(kf1b, qA, minit, 0, 0, 0);
      __builtin_amdgcn_s_setprio(0);
      f32x4 p0, p1, p2, p3;
#pragma unroll
      for (int r = 0; r < 4; ++r) {
        p0[r] = __builtin_amdgcn_exp2f(e0[r]);
        p1[r] = __builtin_amdgcn_exp2f(e1[r]);
        p2[r] = __builtin_amdgcn_exp2f(e2[r]);
        p3[r] = __builtin_amdgcn_exp2f(e3[r]);
      }
      uint4 uA = make_uint4(cvtpk(p0[0], p0[1]), cvtpk(p0[2], p0[3]),
                            cvtpk(p1[0], p1[1]), cvtpk(p1[2], p1[3]));
      uint4 uB = make_uint4(cvtpk(p2[0], p2[1]), cvtpk(p2[2], p2[3]),
                            cvtpk(p3[0], p3[1]), cvtpk(p3[2], p3[3]));
      s16x8 fpa = __builtin_bit_cast(s16x8, uA);
      s16x8 fpb = __builtin_bit_cast(s16x8, uB);

      __builtin_amdgcn_s_setprio(1);
      oA0 = __builtin_amdgcn_mfma_f32_16x16x32_bf16(a0a, fpa, oA0, 0, 0, 0);
      oA1 = __builtin_amdgcn_mfma_f32_16x16x32_bf16(a1a, fpa, oA1, 0, 0, 0);
      lac = __builtin_amdgcn_mfma_f32_16x16x32_bf16(ones, fpa, lac, 0, 0, 0);
      oA0 = __builtin_amdgcn_mfma_f32_16x16x32_bf16(a0b, fpb, oA0, 0, 0, 0);
      oA1 = __builtin_amdgcn_mfma_f32_16x16x32_bf16(a1b, fpb, oA1, 0, 0, 0);
      lac = __builtin_amdgcn_mfma_f32_16x16x32_bf16(ones, fpb, lac, 0, 0, 0);
      __builtin_amdgcn_s_setprio(0);
    }
    if (t < 15) WRITES((t + 1) & 1)
    __syncthreads();
  }
#undef LOADG
#undef WRITES

  // combine 4 key-quarters (additive: fixed softmax shift)
  if (kh != 0) {
    u.ph1.pO0[kh - 1][wid2][lane] = oA0;
    u.ph1.pO1[kh - 1][wid2][lane] = oA1;
    u.ph1.pL[kh - 1][wid2][lane] = lac[0];
  }
  __syncthreads();
  if (kh == 0) {
    float L = lac[0];
    f32x4 t0 = oA0, t1 = oA1;
#pragma unroll
    for (int q = 0; q < 3; ++q) {
      f32x4 q0 = u.ph1.pO0[q][wid2][lane], q1 = u.ph1.pO1[q][wid2][lane];
      L += u.ph1.pL[q][wid2][lane];
#pragma unroll
      for (int r = 0; r < 4; ++r) { t0[r] += q0[r]; t1[r] += q1[r]; }
    }
    float sc = beta[0] / L;
    int rloc = wid2 * 16 + c16;
    f32x4 v0, v1;
#pragma unroll
    for (int r = 0; r < 4; ++r) { v0[r] = t0[r] * sc; v1[r] = t1[r] * sc; }
    *(f32x4*)&sS[rloc][4 * g] = v0;
    *(f32x4*)&sS[rloc][16 + 4 * g] = v1;
  }
  __syncthreads();
  u.ph2.wc[tid] = ((const float4*)wch)[tid];
  u.ph2.wp[tid] = ((const float4*)(w2 + (size_t)b * 4096))[tid];
  __syncthreads();

  if (tid < 416) {
    int row2 = tid >> 3, fq = tid & 7;
    int hw_l = row2 / 13, dout = row2 % 13;
    int rbase = hw_l * 16 + dout;
    size_t xrow = ((size_t)b * 4096 + (size_t)(rg * 4 + hw_l) * 16 + dout) * 32;
    float accC[4], accP[4];
#pragma unroll
    for (int j = 0; j < 4; ++j) { accC[j] = bcS[fq * 4 + j]; accP[j] = bpS[fq * 4 + j]; }
    for (int kd = 0; kd < 4; ++kd) {
      const float4* xr4 = (const float4*)(x + xrow + (size_t)kd * 32);
      const float* srow2 = sS[rbase + kd];
#pragma unroll
      for (int c4 = 0; c4 < 8; ++c4) {
        float4 xv = xr4[c4];
#pragma unroll
        for (int e = 0; e < 4; ++e) {
          float xve = (e == 0 ? xv.x : e == 1 ? xv.y : e == 2 ? xv.z : xv.w);
          float cve = srow2[4 * c4 + e] + xve;
          int wbase = (kd * 32 + 4 * c4 + e) * 8 + fq;
          float4 w1 = u.ph2.wc[wbase];
          accC[0] = fmaf(cve, w1.x, accC[0]);
          accC[1] = fmaf(cve, w1.y, accC[1]);
          accC[2] = fmaf(cve, w1.z, accC[2]);
          accC[3] = fmaf(cve, w1.w, accC[3]);
          float4 w2v = u.ph2.wp[wbase];
          accP[0] = fmaf(xve, w2v.x, accP[0]);
          accP[1] = fmaf(xve, w2v.y, accP[1]);
          accP[2] = fmaf(xve, w2v.z, accP[2]);
          accP[3] = fmaf(xve, w2v.w, accP[3]);
        }
      }
    }
    int gid = b * 3328 + (rg * 4 + hw_l) * 13 + dout;
    float* orow = out + (size_t)gid * 32 + fq * 4;
    float4 o;
    o.x = fmaxf(accC[0], 0.f) + fmaxf(accP[0], 0.f);
    o.y = fmaxf(accC[1], 0.f) + fmaxf(accP[1], 0.f);
    o.z = fmaxf(accC[2], 0.f) + fmaxf(accP[2], 0.f);
    o.w = fmaxf(accC[3], 0.f) + fmaxf(accP[3], 0.f);
    *(float4*)orow = o;
  }
}

extern "C" void kernel_launch(void* const* d_in, const int* in_sizes, int n_in,
                              void* d_out, int out_size, void* d_ws, size_t ws_size,
                              hipStream_t stream)
{
  const float* x     = (const float*)d_in[0];
  const float* beta  = (const float*)d_in[1];
  const float* wq    = (const float*)d_in[2];
  const float* bq    = (const float*)d_in[3];
  const float* wk    = (const float*)d_in[4];
  const float* bk    = (const float*)d_in[5];
  const float* wv    = (const float*)d_in[6];
  const float* bv    = (const float*)d_in[7];
  const float* gamma = (const float*)d_in[8];
  const float* wch   = (const float*)d_in[9];
  const float* bch   = (const float*)d_in[10];
  const float* wpos  = (const float*)d_in[11];
  const float* bpos  = (const float*)d_in[12];
  float* out = (float*)d_out;
  float* ws  = (float*)d_ws;

  ushort* xb  = (ushort*)(ws + 0);        // 512 KB
  ushort* xtf = (ushort*)(ws + 262144);   // 512 KB
  float*  w2  = ws + 524288;              // 64 KB
  float*  b2  = ws + 540672;              // 512 B
  float*  pG  = ws + 540800;              // 512 KB
  float*  pS  = ws + 671872;              // 16 KB

  hipLaunchKernelGGL(k_prep,  dim3(256),   dim3(256),  0, stream, x, xb, xtf);
  hipLaunchKernelGGL(k_gramP, dim3(32),    dim3(256),  0, stream, xtf, pG, pS);
  hipLaunchKernelGGL(k_alg,   dim3(4),     dim3(1024), 0, stream,
                     pG, pS, wq, bq, wk, bk, wv, bv, gamma, wpos, bpos, w2, b2);
  hipLaunchKernelGGL(k_fused, dim3(64, 4), dim3(1024), 0, stream,
                     xb, xtf, x, beta, wch, bch, w2, b2, out);
}